// Round 1
// baseline (152.914 us; speedup 1.0000x reference)
//
#include <hip/hip_runtime.h>

// LieSE3: per row [x, y, p_yaw] -> 4x4 SE(3) matrix with z-only rotation.
//
// Closed form (w = 0.1*p, ts = w^2, th = |w|):
//   A  = sin(th)/(th+eps);  Bc = (1-cos th)/(ts+eps);  C = (1-A)/(ts+eps)
//   R00 = R11 = 1 - Bc*ts;  R10 = A*w = -R01;  R22 = 1
//   V00 = V11 = 1 - C*ts;   V10 = Bc*w = -V01
//   t0 = V00*x - Bc*w*y;  t1 = Bc*w*x + V00*y;  t2 = 0
// Output matrix rows 2 and 3 are constants [0,0,1,0], [0,0,0,1].
//
// Scheme: 4 threads per matrix; thread writes one float4 (one matrix row).
// Store instructions are perfectly contiguous (64 lanes x 16B = 1KB/instr).
// Input reads are 4x redundant but broadcast within quads -> L1 absorbs.

#define ROTATION_SCALE 0.1f
#define EPS_F 1e-5f

__global__ __launch_bounds__(256) void lie_se3_kernel(
    const float* __restrict__ uv, float4* __restrict__ out, int B) {
  int t = blockIdx.x * blockDim.x + threadIdx.x;
  int row = t >> 2;
  int part = t & 3;
  if (row >= B) return;

  float x = uv[3 * row + 0];
  float y = uv[3 * row + 1];
  float p = uv[3 * row + 2];

  float w = p * ROTATION_SCALE;
  float ts = w * w;
  float th = fabsf(w);
  float s, c;
  sincosf(th, &s, &c);
  float A  = s / (th + EPS_F);
  float Bc = (1.0f - c) / (ts + EPS_F);
  float C  = (1.0f - A) / (ts + EPS_F);

  float R00 = 1.0f - Bc * ts;   // == R11
  float Aw  = A * w;            // R10 = Aw, R01 = -Aw
  float V00 = 1.0f - C * ts;    // == V11
  float Bw  = Bc * w;           // V10 = Bw, V01 = -Bw
  float t0 = V00 * x - Bw * y;
  float t1 = Bw * x + V00 * y;

  float4 v;
  v.x = (part == 0) ? R00 : ((part == 1) ? Aw : 0.0f);
  v.y = (part == 0) ? -Aw : ((part == 1) ? R00 : 0.0f);
  v.z = (part == 2) ? 1.0f : 0.0f;
  v.w = (part == 0) ? t0 : ((part == 1) ? t1 : ((part == 3) ? 1.0f : 0.0f));

  out[t] = v;
}

extern "C" void kernel_launch(void* const* d_in, const int* in_sizes, int n_in,
                              void* d_out, int out_size, void* d_ws, size_t ws_size,
                              hipStream_t stream) {
  const float* uv = (const float*)d_in[0];
  float4* out = (float4*)d_out;
  int B = in_sizes[0] / 3;            // 2,000,000
  long long threads = 4LL * B;        // one float4 (matrix row) per thread
  int block = 256;
  int grid = (int)((threads + block - 1) / block);
  lie_se3_kernel<<<grid, block, 0, stream>>>(uv, out, B);
}

// Round 2
// 149.740 us; speedup vs baseline: 1.0212x; 1.0212x over previous
//
#include <hip/hip_runtime.h>

// LieSE3: per row [x, y, p_yaw] -> 4x4 SE(3) matrix with z-only rotation.
//
// Closed form (w = 0.1*p, ts = w^2, th = |w|):
//   A  = sin(th)/(th+eps);  Bc = (1-cos th)/(ts+eps);  C = (1-A)/(ts+eps)
//   R00 = R11 = 1 - Bc*ts;  R10 = A*w = -R01;  R22 = 1
//   V00 = V11 = 1 - C*ts;   V10 = Bc*w = -V01
//   t0 = V00*x - Bc*w*y;  t1 = Bc*w*x + V00*y;  t2 = 0
// Output matrix rows 2 and 3 are constants [0,0,1,0], [0,0,0,1].
//
// Scheme: 4 threads per matrix; thread writes one float4 (one matrix row).
// Store instructions are perfectly contiguous (64 lanes x 16B = 1KB/instr).
//
// R1 change: sincosf -> __sinf/__cosf. The OCML sincos libcall takes the
// cosine result by pointer; when the alloca isn't promoted this becomes
// per-thread SCRATCH traffic + a branchy range-reduction path. Native
// v_sin_f32/v_cos_f32 are ~4 ULP (plenty under the 1e-1 threshold; |theta|
// <= ~0.55 here) and branch/scratch-free.

#define ROTATION_SCALE 0.1f
#define EPS_F 1e-5f

__global__ __launch_bounds__(256) void lie_se3_kernel(
    const float* __restrict__ uv, float4* __restrict__ out, int B) {
  int t = blockIdx.x * blockDim.x + threadIdx.x;
  int row = t >> 2;
  int part = t & 3;
  if (row >= B) return;

  float x = uv[3 * row + 0];
  float y = uv[3 * row + 1];
  float p = uv[3 * row + 2];

  float w = p * ROTATION_SCALE;
  float ts = w * w;
  float th = fabsf(w);
  float s = __sinf(th);   // v_sin_f32 (+ 1/2pi range-reduction mul)
  float c = __cosf(th);   // v_cos_f32
  float A  = s / (th + EPS_F);
  float Bc = (1.0f - c) / (ts + EPS_F);
  float C  = (1.0f - A) / (ts + EPS_F);

  float R00 = 1.0f - Bc * ts;   // == R11
  float Aw  = A * w;            // R10 = Aw, R01 = -Aw
  float V00 = 1.0f - C * ts;    // == V11
  float Bw  = Bc * w;           // V10 = Bw, V01 = -Bw
  float t0 = V00 * x - Bw * y;
  float t1 = Bw * x + V00 * y;

  float4 v;
  v.x = (part == 0) ? R00 : ((part == 1) ? Aw : 0.0f);
  v.y = (part == 0) ? -Aw : ((part == 1) ? R00 : 0.0f);
  v.z = (part == 2) ? 1.0f : 0.0f;
  v.w = (part == 0) ? t0 : ((part == 1) ? t1 : ((part == 3) ? 1.0f : 0.0f));

  out[t] = v;
}

extern "C" void kernel_launch(void* const* d_in, const int* in_sizes, int n_in,
                              void* d_out, int out_size, void* d_ws, size_t ws_size,
                              hipStream_t stream) {
  const float* uv = (const float*)d_in[0];
  float4* out = (float4*)d_out;
  int B = in_sizes[0] / 3;            // 2,000,000
  long long threads = 4LL * B;        // one float4 (matrix row) per thread
  int block = 256;
  int grid = (int)((threads + block - 1) / block);
  lie_se3_kernel<<<grid, block, 0, stream>>>(uv, out, B);
}

// Round 3
// 140.270 us; speedup vs baseline: 1.0901x; 1.0675x over previous
//
#include <hip/hip_runtime.h>

// LieSE3: per row [x, y, p_yaw] -> 4x4 SE(3) matrix with z-only rotation.
//
// Closed form (w = 0.1*p, ts = w^2, th = |w|):
//   A  = sin(th)/(th+eps);  Bc = (1-cos th)/(ts+eps);  C = (1-A)/(ts+eps)
//   R00 = R11 = 1 - Bc*ts;  R10 = A*w = -R01;  R22 = 1
//   V00 = V11 = 1 - C*ts;   V10 = Bc*w = -V01
//   t0 = V00*x - Bw*y;  t1 = Bw*x + V00*y;  rows 2,3 = [0,0,1,0],[0,0,0,1]
//
// R2 change: 1 thread = 1 matrix (was 4 threads/matrix). Removes the 4x
// redundant loads (96MB->24MB of load requests) and 4x redundant
// divide/trig chains. Output staged through LDS so the global store phase
// stays perfectly contiguous: thread tid stores out[base + tid + k*256]
// from smem[tid + k*256] (ds_read_b128 contiguous = conflict-free,
// global_store_dwordx4 = 1KB/wave-instr).

#define ROTATION_SCALE 0.1f
#define EPS_F 1e-5f

__global__ __launch_bounds__(256) void lie_se3_kernel(
    const float* __restrict__ uv, float4* __restrict__ out, int B) {
  __shared__ float4 smem[1024];  // 256 matrices x 4 rows x 16B = 16 KB

  int tid = threadIdx.x;
  int m = blockIdx.x * 256 + tid;  // matrix index

  float x = 0.0f, y = 0.0f, p = 0.0f;
  if (m < B) {
    x = uv[3 * m + 0];
    y = uv[3 * m + 1];
    p = uv[3 * m + 2];
  }

  float w = p * ROTATION_SCALE;
  float ts = w * w;
  float th = fabsf(w);
  float s = __sinf(th);
  float c = __cosf(th);
  float A  = s / (th + EPS_F);
  float Bc = (1.0f - c) / (ts + EPS_F);
  float C  = (1.0f - A) / (ts + EPS_F);

  float R00 = 1.0f - Bc * ts;  // == R11
  float Aw  = A * w;           // R10 = Aw, R01 = -Aw
  float V00 = 1.0f - C * ts;   // == V11
  float Bw  = Bc * w;          // V10 = Bw, V01 = -Bw
  float t0 = V00 * x - Bw * y;
  float t1 = Bw * x + V00 * y;

  // smem[j] = matrix (j>>2) within this block, row (j&3)
  smem[4 * tid + 0] = make_float4(R00, -Aw, 0.0f, t0);
  smem[4 * tid + 1] = make_float4(Aw, R00, 0.0f, t1);
  smem[4 * tid + 2] = make_float4(0.0f, 0.0f, 1.0f, 0.0f);
  smem[4 * tid + 3] = make_float4(0.0f, 0.0f, 0.0f, 1.0f);
  __syncthreads();

  long long base = (long long)blockIdx.x * 1024;  // float4 index of block start
  long long limit = 4LL * B;
  #pragma unroll
  for (int k = 0; k < 4; ++k) {
    int idx = tid + k * 256;
    long long g = base + idx;
    if (g < limit) out[g] = smem[idx];
  }
}

extern "C" void kernel_launch(void* const* d_in, const int* in_sizes, int n_in,
                              void* d_out, int out_size, void* d_ws, size_t ws_size,
                              hipStream_t stream) {
  const float* uv = (const float*)d_in[0];
  float4* out = (float4*)d_out;
  int B = in_sizes[0] / 3;  // 2,000,000
  int block = 256;
  int grid = (B + block - 1) / block;  // one thread per matrix
  lie_se3_kernel<<<grid, block, 0, stream>>>(uv, out, B);
}